// Round 9
// baseline (274.955 us; speedup 1.0000x reference)
//
#include <hip/hip_runtime.h>
#include <hip/hip_bf16.h>
#include <math.h>

typedef __bf16 bf16x4 __attribute__((ext_vector_type(4)));
typedef __bf16 bf16x8 __attribute__((ext_vector_type(8)));
typedef float  f32x4  __attribute__((ext_vector_type(4)));

#define S_LEN 2048
#define BATCH 4
#define DMODEL 1280
#define NHEAD 16
#define DHEAD 80
#define KDIM 1280

__device__ __forceinline__ f32x4 mfma_bf16(bf16x8 a, bf16x8 b, f32x4 c) {
  return __builtin_amdgcn_mfma_f32_16x16x32_bf16(a, b, c, 0, 0, 0);
}

__device__ __forceinline__ void gload16(const void* g, void* l) {
  __builtin_amdgcn_global_load_lds(
      (const __attribute__((address_space(1))) unsigned int*)g,
      (__attribute__((address_space(3))) unsigned int*)l, 16, 0, 0);
}

// ---------------- fp32 -> bf16 cast (vectorized) ----------------
__global__ void cast_f32_to_bf16(const float* __restrict__ in,
                                 __bf16* __restrict__ out, int n4) {
  int i = blockIdx.x * 256 + threadIdx.x;
  if (i >= n4) return;
  float4 v = reinterpret_cast<const float4*>(in)[i];
  bf16x4 o;
  o[0] = (__bf16)v.x; o[1] = (__bf16)v.y; o[2] = (__bf16)v.z; o[3] = (__bf16)v.w;
  reinterpret_cast<bf16x4*>(out)[i] = o;
}

// ---------------- sin/cos tables [S][40] ----------------
__global__ void build_sincos(const float* __restrict__ rot,
                             float* __restrict__ ctab, float* __restrict__ stab, int n) {
  int i = blockIdx.x * 256 + threadIdx.x;
  if (i >= n) return;
  float v = rot[i];
  ctab[i] = cosf(v);
  stab[i] = sinf(v);
}

// ---------------- zero page ----------------
__global__ void zero_fill(float* __restrict__ p, int n) {
  int i = blockIdx.x * 256 + threadIdx.x;
  if (i < n) p[i] = 0.0f;
}

// ---------------- QKV GEMM, 128x128 tile, BK=64, 4 waves, SINGLE 32KB buffer ----------------
// m97 regime: small LDS -> 4 blocks/CU (16 waves); stage -> sync -> compute -> sync.
// The stage drain is hidden by the 3 co-resident blocks, not by in-block pipelining.
// Scatters to q[B,H,S,80], k[B,H,S,80], vT[B,H,80,S] (V sigma-permuted per 32-chunk).
__global__ __launch_bounds__(256, 4) void gemm_qkv128(
    const __bf16* __restrict__ A, const __bf16* __restrict__ Bw,
    const float* __restrict__ bias,
    __bf16* __restrict__ qw, __bf16* __restrict__ kw, __bf16* __restrict__ vtw)
{
  __shared__ __align__(1024) char smem[32768];  // A 16KB | B 16KB (single buffer)
  const int tid = threadIdx.x;
  const int lane = tid & 63;
  const int w = tid >> 6;             // 0..3
  const int lr = lane & 15, lg = lane >> 4;
  const int wr = w >> 1, wc = w & 1;  // wave owns rows wr*64..+64, cols wc*64..+64

  // XCD-chunked swizzle: 8 bx-panels per XCD (A slice 2.6 MB, L2-resident)
  const int wg = blockIdx.x;          // 0..1919
  const int xcd = wg & 7, idx = wg >> 3;  // idx 0..239
  const int bx = xcd * 8 + (idx & 7);
  const int by = idx >> 3;            // 0..29
  const int r0 = bx * 128, c0 = by * 128;
  const char* asrc = (const char*)(A + (size_t)r0 * KDIM);
  const char* bsrc = (const char*)(Bw + (size_t)c0 * KDIM);

  f32x4 acc[4][4] = {};

  for (int t = 0; t < 20; ++t) {
    const size_t kb = (size_t)t * 128;  // byte offset into K dim
    // stage tile t: 8 gload16/thread (A 16KB + B 16KB)
#pragma unroll
    for (int i = 0; i < 8; ++i) {
      const int L = i * 4096 + tid * 16;           // 0..32767
      const int r = (L & 16383) >> 7;              // row within A or B panel
      const int coff = (L & 127) ^ ((r & 7) << 4); // inverse-swizzled source
      const char* s = (L < 16384 ? asrc : bsrc) + (size_t)r * 2560 + kb + coff;
      gload16(s, &smem[L]);
    }
    __syncthreads();  // drains vmcnt+lgkm; other blocks on the CU fill the gap

    // compute tile t
#pragma unroll
    for (int kk = 0; kk < 2; ++kk) {
      bf16x8 af[4], bfr[4];
#pragma unroll
      for (int rf = 0; rf < 4; ++rf) {
        const int row = wr * 64 + rf * 16 + lr;
        af[rf] = *reinterpret_cast<const bf16x8*>(
            &smem[row * 128 + ((kk * 64 + lg * 16) ^ ((row & 7) << 4))]);
      }
#pragma unroll
      for (int cf = 0; cf < 4; ++cf) {
        const int row = wc * 64 + cf * 16 + lr;
        bfr[cf] = *reinterpret_cast<const bf16x8*>(
            &smem[16384 + row * 128 + ((kk * 64 + lg * 16) ^ ((row & 7) << 4))]);
      }
#pragma unroll
      for (int rf = 0; rf < 4; ++rf)
#pragma unroll
        for (int cf = 0; cf < 4; ++cf)
          acc[rf][cf] = mfma_bf16(af[rf], bfr[cf], acc[rf][cf]);
    }
    __syncthreads();  // reads done -> next stage may overwrite
  }

  // epilogue: scatter
  const int which = c0 / DMODEL;  // block-uniform (by 0-9 -> q, 10-19 -> k, 20-29 -> v)
  float biasr[4];
#pragma unroll
  for (int cf = 0; cf < 4; ++cf) biasr[cf] = bias[c0 + wc * 64 + cf * 16 + lr];

#pragma unroll
  for (int cf = 0; cf < 4; ++cf) {
    const int c = c0 + wc * 64 + cf * 16 + lr;
    const int ee = c - which * DMODEL;
    const int h = ee / DHEAD;
    const int dh = ee - h * DHEAD;
#pragma unroll
    for (int rf = 0; rf < 4; ++rf)
#pragma unroll
      for (int j = 0; j < 4; ++j) {
        const int r = r0 + wr * 64 + rf * 16 + lg * 4 + j;
        const int s = r >> 2, b = r & 3;
        const __bf16 bv = (__bf16)(acc[rf][cf][j] + biasr[cf]);
        if (which == 0)
          qw[((size_t)(b * NHEAD + h) * S_LEN + s) * DHEAD + dh] = bv;
        else if (which == 1)
          kw[((size_t)(b * NHEAD + h) * S_LEN + s) * DHEAD + dh] = bv;
        else {
          // sigma-permute within each 32-chunk so contiguous 16B = PV A-fragment
          const int sp = (s & ~31) | ((s & 12) << 1) | ((s & 16) >> 2) | (s & 3);
          vtw[((size_t)(b * NHEAD + h) * DHEAD + dh) * S_LEN + sp] = bv;
        }
      }
  }
}

// ---------------- out-proj GEMM (128x128, unchanged from R8) ----------------
template <int MODE>
__global__ __launch_bounds__(256) void gemm_bt(
    const __bf16* __restrict__ A, const __bf16* __restrict__ Bw,
    const float* __restrict__ bias, float* __restrict__ outf)
{
  __shared__ __align__(16) char smem[2][2][16384];
  const int tid = threadIdx.x;
  const int lane = tid & 63;
  const int w = tid >> 6;
  const int lr = lane & 15, lg = lane >> 4;
  const int rowblk = (w >> 1) * 64, colblk = (w & 1) * 64;
  const int sxz = (lane & 7) << 4;

  const int wg = blockIdx.x;
  const int xcd = wg & 7, idx = wg >> 3;
  const int bx = xcd * 8 + (idx & 7);
  const int by = idx >> 3;
  const int r0 = bx * 128;
  const int c0 = by * 128;
  const char* asrc = (const char*)(A + (size_t)r0 * KDIM);
  const char* bsrc = (const char*)(Bw + (size_t)c0 * KDIM);

  f32x4 acc[4][4] = {};

  auto stage = [&](int buf, int kt) {
    const size_t kb = (size_t)kt * 128;
#pragma unroll
    for (int i = 0; i < 4; ++i) {
      int L = i * 4096 + tid * 16;
      int r = L >> 7;
      int coff = (L & 127) ^ ((r & 7) << 4);
      gload16(asrc + (size_t)r * 2560 + kb + coff, &smem[buf][0][L]);
      gload16(bsrc + (size_t)r * 2560 + kb + coff, &smem[buf][1][L]);
    }
  };

  auto compute = [&](int buf) {
#pragma unroll
    for (int kk = 0; kk < 2; ++kk) {
      const int cb = (kk * 64 + lg * 16) ^ sxz;
      bf16x8 af[4], bfr[4];
#pragma unroll
      for (int rf = 0; rf < 4; ++rf)
        af[rf] = *reinterpret_cast<const bf16x8*>(&smem[buf][0][(rowblk + rf * 16 + lr) * 128 + cb]);
#pragma unroll
      for (int cf = 0; cf < 4; ++cf)
        bfr[cf] = *reinterpret_cast<const bf16x8*>(&smem[buf][1][(colblk + cf * 16 + lr) * 128 + cb]);
#pragma unroll
      for (int rf = 0; rf < 4; ++rf)
#pragma unroll
        for (int cf = 0; cf < 4; ++cf)
          acc[rf][cf] = mfma_bf16(af[rf], bfr[cf], acc[rf][cf]);
    }
  };

  stage(0, 0);
  asm volatile("s_waitcnt vmcnt(0)" ::: "memory");
  __builtin_amdgcn_s_barrier();
  __builtin_amdgcn_sched_barrier(0);

  for (int t = 0; t < 20; ++t) {
    const int buf = t & 1;
    if (t < 19) {
      stage(buf ^ 1, t + 1);
      asm volatile("s_waitcnt vmcnt(8)" ::: "memory");
    } else {
      asm volatile("s_waitcnt vmcnt(0)" ::: "memory");
    }
    __builtin_amdgcn_sched_barrier(0);
    __builtin_amdgcn_s_barrier();
    __builtin_amdgcn_sched_barrier(0);

    compute(buf);

    __builtin_amdgcn_sched_barrier(0);
    __builtin_amdgcn_s_barrier();
    __builtin_amdgcn_sched_barrier(0);
  }

  float biasr[4];
#pragma unroll
  for (int cf = 0; cf < 4; ++cf) biasr[cf] = bias[c0 + colblk + cf * 16 + lr];

#pragma unroll
  for (int rf = 0; rf < 4; ++rf)
#pragma unroll
    for (int cf = 0; cf < 4; ++cf) {
      const int c = c0 + colblk + cf * 16 + lr;
#pragma unroll
      for (int j = 0; j < 4; ++j) {
        const int r = r0 + rowblk + rf * 16 + lg * 4 + j;
        outf[(size_t)r * DMODEL + c] = acc[rf][cf][j] + biasr[cf];
      }
    }
}

// ---------------- RoPE in-place on q,k; q additionally pre-scaled by scale*log2e ----------------
__global__ void rope_kernel(__bf16* __restrict__ qw, __bf16* __restrict__ kw,
                            const float* __restrict__ ctab, const float* __restrict__ stab,
                            float qscale)
{
  int idx = blockIdx.x * 256 + threadIdx.x;  // 2*64*2048*10 threads
  const int j = idx % 10;
  int rest = idx / 10;
  const int s = rest & (S_LEN - 1);
  rest >>= 11;
  const int bh = rest & 63;
  const int isk = rest >> 6;
  __bf16* base = (isk ? kw : qw) + ((size_t)bh * S_LEN + s) * DHEAD;
  const float4 c4 = *reinterpret_cast<const float4*>(ctab + s * 40 + j * 4);
  const float4 s4 = *reinterpret_cast<const float4*>(stab + s * 40 + j * 4);
  bf16x4 a = *reinterpret_cast<bf16x4*>(base + j * 4);
  bf16x4 b = *reinterpret_cast<bf16x4*>(base + 40 + j * 4);
  const float m = isk ? 1.0f : qscale;
  const float cc[4] = {c4.x, c4.y, c4.z, c4.w};
  const float ss[4] = {s4.x, s4.y, s4.z, s4.w};
#pragma unroll
  for (int t = 0; t < 4; ++t) {
    float fa = (float)a[t], fb = (float)b[t];
    a[t] = (__bf16)((fa * cc[t] - fb * ss[t]) * m);
    b[t] = (__bf16)((fb * cc[t] + fa * ss[t]) * m);
  }
  *reinterpret_cast<bf16x4*>(base + j * 4) = a;
  *reinterpret_cast<bf16x4*>(base + 40 + j * 4) = b;
}

// ---------------- attention v5 (unchanged from R8) ----------------
__global__ __launch_bounds__(256, 3) void attn_kernel(
    const __bf16* __restrict__ qw, const __bf16* __restrict__ kw,
    const __bf16* __restrict__ vtw, __bf16* __restrict__ ow,
    const float* __restrict__ zp)
{
  __shared__ __align__(1024) char smem[2][24576];  // [buf][K 12KB | V 12KB]

  const int tid = threadIdx.x;
  const int lane = tid & 63;
  const int w = tid >> 6;             // 0..3
  const int lr = lane & 15, lg = lane >> 4;

  const int wg = blockIdx.x;          // 0..1023
  const int local = wg >> 3;
  const int bh = (wg & 7) * 8 + (local >> 4);
  const int qt = local & 15;

  const char* qbase = (const char*)(qw + ((size_t)bh * S_LEN + qt * 128) * DHEAD);
  const char* kbase = (const char*)(kw + (size_t)bh * S_LEN * DHEAD);
  const char* vbase = (const char*)(vtw + (size_t)bh * DHEAD * S_LEN);
  const char* zpb = (const char*)zp;

  bf16x8 z8, one8;
#pragma unroll
  for (int i = 0; i < 8; ++i) { z8[i] = (__bf16)0.0f; one8[i] = (__bf16)1.0f; }

  bf16x8 aq[2][3];
#pragma unroll
  for (int m = 0; m < 2; ++m) {
    const char* rp = qbase + (size_t)(w * 32 + m * 16 + lr) * 160;
    aq[m][0] = *reinterpret_cast<const bf16x8*>(rp + lg * 16);
    aq[m][1] = *reinterpret_cast<const bf16x8*>(rp + 64 + lg * 16);
    aq[m][2] = (lg < 2) ? *reinterpret_cast<const bf16x8*>(rp + 128 + lg * 16) : z8;
  }

  const char* src[6];
  size_t step[6];
#pragma unroll
  for (int i = 0; i < 6; ++i) {
    const int s = w * 6 + i;
    if (s < 12) {
      const int ks = s >> 2, n = s & 3;
      if (ks == 2 && lg >= 2) { src[i] = zpb + lane * 16; step[i] = 0; }
      else { src[i] = kbase + (size_t)(n * 16 + lr) * 160 + ks * 64 + lg * 16; step[i] = 64 * 160; }
    } else {
      const int v = s - 12, mf = v >> 1, ks2 = v & 1;
      if (mf == 5) { src[i] = zpb + lane * 16; step[i] = 0; }
      else { src[i] = vbase + (size_t)(mf * 16 + lr) * 4096 + (size_t)(ks2 * 32 + lg * 8) * 2; step[i] = 128; }
    }
  }

  auto stage = [&](int buf) {
#pragma unroll
    for (int i = 0; i < 6; ++i) {
      gload16(src[i], &smem[buf][(w * 6 + i) * 1024]);
      src[i] += step[i];
    }
  };

  f32x4 accO[5][2] = {};  // O[dh = mf*16+lg*4+j][q = w*32 + m*16 + lr]
  f32x4 accD[2] = {};     // den(q=lr) in every lane/reg via ones-MFMA

  stage(0);
  asm volatile("s_waitcnt vmcnt(0)" ::: "memory");
  __builtin_amdgcn_s_barrier();
  __builtin_amdgcn_sched_barrier(0);

  for (int t = 0; t < 32; ++t) {
    const int buf = t & 1;
    if (t < 31) {
      stage(buf ^ 1);                                  // prefetch stays in flight
      asm volatile("s_waitcnt vmcnt(6)" ::: "memory"); // tile t landed; t+1 flying
    } else {
      asm volatile("s_waitcnt vmcnt(0)" ::: "memory");
    }
    __builtin_amdgcn_sched_barrier(0);
    __builtin_amdgcn_s_barrier();   // tile t visible to all waves
    __builtin_amdgcn_sched_barrier(0);

    const char* Kb = smem[buf];
    const char* Vb = smem[buf] + 12288;

    // S^T = K * Q^T  (Q pre-scaled by scale*log2e, so p = exp2(s))
    f32x4 sc[2][4] = {};
#pragma unroll
    for (int n = 0; n < 4; ++n) {
      bf16x8 af0 = *reinterpret_cast<const bf16x8*>(Kb + (0 * 4 + n) * 1024 + lane * 16);
      bf16x8 af1 = *reinterpret_cast<const bf16x8*>(Kb + (1 * 4 + n) * 1024 + lane * 16);
      bf16x8 af2 = *reinterpret_cast<const bf16x8*>(Kb + (2 * 4 + n) * 1024 + lane * 16);
#pragma unroll
      for (int m = 0; m < 2; ++m) {
        sc[m][n] = mfma_bf16(af0, aq[m][0], sc[m][n]);
        sc[m][n] = mfma_bf16(af1, aq[m][1], sc[m][n]);
        sc[m][n] = mfma_bf16(af2, aq[m][2], sc[m][n]);
      }
    }

    // p = exp2(s); lane-local P pack (permuted k-order)
    bf16x8 bp[2][2];
#pragma unroll
    for (int m = 0; m < 2; ++m)
#pragma unroll
      for (int n = 0; n < 4; ++n) {
#pragma unroll
        for (int j = 0; j < 4; ++j)
          bp[m][n >> 1][(n & 1) * 4 + j] = (__bf16)__builtin_amdgcn_exp2f(sc[m][n][j]);
      }

    // O += P*V (V pre-permuted in global); den += ones*P on the MFMA pipe
#pragma unroll
    for (int ks2 = 0; ks2 < 2; ++ks2) {
#pragma unroll
      for (int mf = 0; mf < 5; ++mf) {
        bf16x8 av = *reinterpret_cast<const bf16x8*>(Vb + (mf * 2 + ks2) * 1024 + lane * 16);
        accO[mf][0] = mfma_bf16(av, bp[0][ks2], accO[mf][0]);
        accO[mf][1] = mfma_bf16(av, bp[1][ks2], accO[mf][1]);
      }
      accD[0] = mfma_bf16(one8, bp[0][ks2], accD[0]);
      accD[1] = mfma_bf16(one8, bp[1][ks2], accD[1]);
    }

    __builtin_amdgcn_sched_barrier(0);
    __builtin_amdgcn_s_barrier();   // reads done -> next iter may overwrite buf^1
    __builtin_amdgcn_sched_barrier(0);
  }

  __syncthreads();

  float rinv[2];
#pragma unroll
  for (int m = 0; m < 2; ++m) rinv[m] = 1.0f / accD[m][0];

  char* sOut = smem[0];
#pragma unroll
  for (int mf = 0; mf < 5; ++mf)
#pragma unroll
    for (int m = 0; m < 2; ++m) {
      bf16x4 o4;
#pragma unroll
      for (int j = 0; j < 4; ++j) o4[j] = (__bf16)(accO[mf][m][j] * rinv[m]);
      *reinterpret_cast<bf16x4*>(sOut + (size_t)(w * 32 + m * 16 + lr) * 160 + (mf * 16 + lg * 4) * 2) = o4;
    }
  __syncthreads();

  const int b = bh >> 4, h = bh & 15;
#pragma unroll
  for (int i = 0; i < 5; ++i) {
    int c = i * 256 + tid;
    int row = c / 10, slot = c - row * 10;
    int token = (qt * 128 + row) * 4 + b;
    *reinterpret_cast<bf16x8*>((char*)ow + (size_t)token * 2560 + h * 160 + slot * 16) =
        *reinterpret_cast<const bf16x8*>(sOut + row * 160 + slot * 16);
  }
}

// ---------------- launcher ----------------
extern "C" void kernel_launch(void* const* d_in, const int* in_sizes, int n_in,
                              void* d_out, int out_size, void* d_ws, size_t ws_size,
                              hipStream_t stream)
{
  const float* hidden = (const float*)d_in[0];
  const float* rot    = (const float*)d_in[1];
  const float* w1     = (const float*)d_in[2];
  const float* b1     = (const float*)d_in[3];
  const float* w2     = (const float*)d_in[4];
  const float* b2     = (const float*)d_in[5];
  float* out = (float*)d_out;

  char* ws = (char*)d_ws;
  __bf16* Xbf  = (__bf16*)(ws);                 // 8192x1280 bf16      = 20,971,520 B
  __bf16* W1bf = (__bf16*)(ws + 20971520);      // 3840x1280 bf16      =  9,830,400 B
  __bf16* W2bf = (__bf16*)(ws + 30801920);      // 1280x1280 bf16      =  3,276,800 B
  float*  ctab = (float*)(ws + 34078720);       // 2048x40 f32         =    327,680 B
  float*  stab = (float*)(ws + 34406400);       //                     =    327,680 B
  __bf16* qwp  = (__bf16*)(ws + 34734080);      // [B,H,S,80] bf16     = 20,971,520 B
  __bf16* kwp  = (__bf16*)(ws + 55705600);      // [B,H,S,80] bf16     = 20,971,520 B
  __bf16* vtwp = (__bf16*)(ws + 76677120);      // [B,H,80,S] bf16 (sigma-permuted) = 20,971,520 B
  __bf16* owp  = (__bf16*)(ws + 97648640);      // [S*B,1280] bf16     = 20,971,520 B
  float*  zp   = (float*)(ws + 118620160);      // 4KB zero page

  cast_f32_to_bf16<<<10240, 256, 0, stream>>>(hidden, Xbf, 2621440);
  cast_f32_to_bf16<<<4800, 256, 0, stream>>>(w1, W1bf, 1228800);
  cast_f32_to_bf16<<<1600, 256, 0, stream>>>(w2, W2bf, 409600);
  build_sincos<<<320, 256, 0, stream>>>(rot, ctab, stab, 81920);
  zero_fill<<<4, 256, 0, stream>>>(zp, 1024);

  gemm_qkv128<<<1920, 256, 0, stream>>>(Xbf, W1bf, b1, qwp, kwp, vtwp);

  const float qscale = 1.4426950408889634f / sqrtf(80.0f);  // scale * log2(e), folded into Q
  rope_kernel<<<10240, 256, 0, stream>>>(qwp, kwp, ctab, stab, qscale);

  attn_kernel<<<1024, 256, 0, stream>>>(qwp, kwp, vtwp, owp, zp);

  gemm_bt<1><<<640, 256, 0, stream>>>(owp, W2bf, b2, out);
}

// Round 10
// 274.143 us; speedup vs baseline: 1.0030x; 1.0030x over previous
//
#include <hip/hip_runtime.h>
#include <hip/hip_bf16.h>
#include <math.h>

typedef __bf16 bf16x4 __attribute__((ext_vector_type(4)));
typedef __bf16 bf16x8 __attribute__((ext_vector_type(8)));
typedef float  f32x4  __attribute__((ext_vector_type(4)));

#define S_LEN 2048
#define BATCH 4
#define DMODEL 1280
#define NHEAD 16
#define DHEAD 80
#define KDIM 1280

__device__ __forceinline__ f32x4 mfma_bf16(bf16x8 a, bf16x8 b, f32x4 c) {
  return __builtin_amdgcn_mfma_f32_16x16x32_bf16(a, b, c, 0, 0, 0);
}

__device__ __forceinline__ void gload16(const void* g, void* l) {
  __builtin_amdgcn_global_load_lds(
      (const __attribute__((address_space(1))) unsigned int*)g,
      (__attribute__((address_space(3))) unsigned int*)l, 16, 0, 0);
}

#define SB0 __builtin_amdgcn_sched_barrier(0)
#define BARRIER __builtin_amdgcn_s_barrier()
#define LGKM0 do { asm volatile("s_waitcnt lgkmcnt(0)" ::: "memory"); SB0; } while (0)
#define VM2   do { SB0; asm volatile("s_waitcnt vmcnt(2)" ::: "memory"); SB0; } while (0)

// ---------------- fp32 -> bf16 cast (vectorized) ----------------
__global__ void cast_f32_to_bf16(const float* __restrict__ in,
                                 __bf16* __restrict__ out, int n4) {
  int i = blockIdx.x * 256 + threadIdx.x;
  if (i >= n4) return;
  float4 v = reinterpret_cast<const float4*>(in)[i];
  bf16x4 o;
  o[0] = (__bf16)v.x; o[1] = (__bf16)v.y; o[2] = (__bf16)v.z; o[3] = (__bf16)v.w;
  reinterpret_cast<bf16x4*>(out)[i] = o;
}

// ---------------- sin/cos tables [S][40] ----------------
__global__ void build_sincos(const float* __restrict__ rot,
                             float* __restrict__ ctab, float* __restrict__ stab, int n) {
  int i = blockIdx.x * 256 + threadIdx.x;
  if (i >= n) return;
  float v = rot[i];
  ctab[i] = cosf(v);
  stab[i] = sinf(v);
}

// ---------------- zero page ----------------
__global__ void zero_fill(float* __restrict__ p, int n) {
  int i = blockIdx.x * 256 + threadIdx.x;
  if (i < n) p[i] = 0.0f;
}

// ---------------- QKV GEMM, 256x256, BK=64, 8 waves, 8-phase counted-vmcnt ----------------
// m201-class template. Per 2 K-tiles (S0=even buf, S1=odd buf): 8 phases of
// {ds_read subtile | 2 gload16 | barrier | lgkmcnt(0) | setprio+16 MFMA | barrier}.
// Per-wave staging ownership: wave (wr,wc) stages the A rows [wr*128+wc*32, +32) and
// B rows [wc*64+wr*32, +32) it reads -> wave-local vmcnt = landing proof (+barrier).
// Region-death schedule (all gload targets dead >=1 phase, barrier-separated):
//   P1: B(S1,taub,p1)   [S1.B dead since P7(prev)]   P2: A(S1,taub,p0) [dead since P8(prev)]
//   P3: A(S1,taub,p1)   P4: B(S0,taua+2,p0) [S0.B dead since P3]  P5: B(S0,taua+2,p1)
//   P6: A(S0,taua+2,p0) [S0.A dead since P4]  P7: A(S0,taua+2,p1)  P8: B(S1,taub+2,p0)
// vmcnt(2) ledger: end-P4 outstanding={P8',P1,P2,P3,P4}=10 -> oldest 8 landed = all of taub
//   (read P5); end-P8 outstanding={P4..P8}=10 -> oldest 8 = taua+2 complete (read next P1).
__global__ __launch_bounds__(512, 2) void gemm_qkv256(
    const __bf16* __restrict__ A, const __bf16* __restrict__ Bw,
    const float* __restrict__ bias,
    __bf16* __restrict__ qw, __bf16* __restrict__ kw, __bf16* __restrict__ vtw)
{
  __shared__ __align__(1024) char smem[2][65536];  // [buf][A 32KB | B 32KB]
  const int tid = threadIdx.x;
  const int lane = tid & 63;
  const int w = tid >> 6;             // 0..7
  const int lr = lane & 15, lg = lane >> 4;
  const int wr = w >> 2, wc = w & 3;  // wave owns C rows wr*128..+128, cols wc*64..+64

  const int wg = blockIdx.x;          // 0..479, XCD-chunked
  const int xcd = wg & 7, idx = wg >> 3;
  const int bx = xcd * 4 + (idx & 3);
  const int by = idx >> 2;
  const int r0 = bx * 256, c0 = by * 256;
  const char* asrc = (const char*)(A + (size_t)r0 * KDIM);
  const char* bsrc = (const char*)(Bw + (size_t)c0 * KDIM);

  // staging source (pre-swizzled global, m173): lane l covers row +l>>3, slot (l&7)^(l>>3)
  const int lrow8 = lane >> 3;
  const int lsl = (lane & 7) ^ lrow8;
  const char* aSrcB = asrc + (size_t)(wr * 128 + wc * 32 + lrow8) * 2560 + lsl * 16;
  const char* bSrcB = bsrc + (size_t)(wc * 64 + wr * 32 + lrow8) * 2560 + lsl * 16;
  const int aDstR = wr * 128 + wc * 32;   // wave's A staging row base
  const int bDstR = wc * 64 + wr * 32;    // wave's B staging row base

  auto issueA = [&](int buf, int kt, int pair) {
#pragma unroll
    for (int q = 0; q < 2; ++q) {
      const int li = pair * 2 + q;
      gload16(aSrcB + (size_t)kt * 128 + (size_t)li * 8 * 2560,
              &smem[buf][(aDstR + li * 8) * 128 + lane * 16]);
    }
  };
  auto issueB = [&](int buf, int kt, int pair) {
#pragma unroll
    for (int q = 0; q < 2; ++q) {
      const int li = pair * 2 + q;
      gload16(bSrcB + (size_t)kt * 128 + (size_t)li * 8 * 2560,
              &smem[buf][32768 + (bDstR + li * 8) * 128 + lane * 16]);
    }
  };

  f32x4 acc[8][4] = {};
  bf16x8 af[4], bfr[4];

  auto ldsA = [&](const char* Sb, int kk, int rtb) {
#pragma unroll
    for (int i = 0; i < 4; ++i) {
      const int row = wr * 128 + (rtb + i) * 16 + lr;
      af[i] = *reinterpret_cast<const bf16x8*>(
          &Sb[row * 128 + ((kk * 64 + lg * 16) ^ ((row & 7) << 4))]);
    }
  };
  auto ldsB = [&](const char* Sb, int kk) {
#pragma unroll
    for (int ct = 0; ct < 4; ++ct) {
      const int row = wc * 64 + ct * 16 + lr;
      bfr[ct] = *reinterpret_cast<const bf16x8*>(
          &Sb[32768 + row * 128 + ((kk * 64 + lg * 16) ^ ((row & 7) << 4))]);
    }
  };
  auto mfma16 = [&](int rtb) {
    __builtin_amdgcn_s_setprio(1);
#pragma unroll
    for (int i = 0; i < 4; ++i)
#pragma unroll
      for (int ct = 0; ct < 4; ++ct)
        acc[rtb + i][ct] = mfma_bf16(af[i], bfr[ct], acc[rtb + i][ct]);
    __builtin_amdgcn_s_setprio(0);
  };

  // prologue: tau0 full + tau1 B-pair0 (10 loads/wave), drain, barrier
  issueA(0, 0, 0); issueA(0, 0, 1);
  issueB(0, 0, 0); issueB(0, 0, 1);
  issueB(1, 1, 0);
  asm volatile("s_waitcnt vmcnt(0)" ::: "memory");
  BARRIER; SB0;

  const char* S0 = smem[0];
  const char* S1 = smem[1];

  for (int it = 0; it < 10; ++it) {
    const int ta = 2 * it, tb = 2 * it + 1;
    // P1
    ldsA(S0, 0, 0); ldsB(S0, 0);
    issueB(1, tb, 1);
    SB0; BARRIER; LGKM0;
    mfma16(0);
    SB0; BARRIER; SB0;
    // P2
    ldsA(S0, 0, 4);
    issueA(1, tb, 0);
    SB0; BARRIER; LGKM0;
    mfma16(4);
    SB0; BARRIER; SB0;
    // P3
    ldsA(S0, 1, 0); ldsB(S0, 1);
    issueA(1, tb, 1);
    SB0; BARRIER; LGKM0;
    mfma16(0);
    SB0; BARRIER; SB0;
    // P4
    ldsA(S0, 1, 4);
    issueB(0, ta + 2, 0);
    VM2;
    BARRIER; LGKM0;
    mfma16(4);
    SB0; BARRIER; SB0;
    // P5
    ldsA(S1, 0, 0); ldsB(S1, 0);
    issueB(0, ta + 2, 1);
    SB0; BARRIER; LGKM0;
    mfma16(0);
    SB0; BARRIER; SB0;
    // P6
    ldsA(S1, 0, 4);
    issueA(0, ta + 2, 0);
    SB0; BARRIER; LGKM0;
    mfma16(4);
    SB0; BARRIER; SB0;
    // P7
    ldsA(S1, 1, 0); ldsB(S1, 1);
    issueA(0, ta + 2, 1);
    SB0; BARRIER; LGKM0;
    mfma16(0);
    SB0; BARRIER; SB0;
    // P8
    ldsA(S1, 1, 4);
    issueB(1, tb + 2, 0);
    VM2;
    BARRIER; LGKM0;
    mfma16(4);
    SB0; BARRIER; SB0;
  }

  // epilogue: scatter (identical to R7 256-square epilogue)
  const int which = c0 / DMODEL;  // 1280 = 5 x 256: tiles never straddle q/k/v
  float biasr[4];
#pragma unroll
  for (int ct = 0; ct < 4; ++ct) biasr[ct] = bias[c0 + wc * 64 + ct * 16 + lr];

#pragma unroll
  for (int ct = 0; ct < 4; ++ct) {
    const int c = c0 + wc * 64 + ct * 16 + lr;
    const int ee = c - which * DMODEL;
    const int h = ee / DHEAD;
    const int dh = ee - h * DHEAD;
#pragma unroll
    for (int rt = 0; rt < 8; ++rt)
#pragma unroll
      for (int j = 0; j < 4; ++j) {
        const int r = r0 + wr * 128 + rt * 16 + lg * 4 + j;
        const int s = r >> 2, b = r & 3;
        const __bf16 bv = (__bf16)(acc[rt][ct][j] + biasr[ct]);
        if (which == 0)
          qw[((size_t)(b * NHEAD + h) * S_LEN + s) * DHEAD + dh] = bv;
        else if (which == 1)
          kw[((size_t)(b * NHEAD + h) * S_LEN + s) * DHEAD + dh] = bv;
        else {
          const int sp = (s & ~31) | ((s & 12) << 1) | ((s & 16) >> 2) | (s & 3);
          vtw[((size_t)(b * NHEAD + h) * DHEAD + dh) * S_LEN + sp] = bv;
        }
      }
  }
}

// ---------------- out-proj GEMM (128x128, unchanged from R9) ----------------
template <int MODE>
__global__ __launch_bounds__(256) void gemm_bt(
    const __bf16* __restrict__ A, const __bf16* __restrict__ Bw,
    const float* __restrict__ bias, float* __restrict__ outf)
{
  __shared__ __align__(16) char smem[2][2][16384];
  const int tid = threadIdx.x;
  const int lane = tid & 63;
  const int w = tid >> 6;
  const int lr = lane & 15, lg = lane >> 4;
  const int rowblk = (w >> 1) * 64, colblk = (w & 1) * 64;
  const int sxz = (lane & 7) << 4;

  const int wg = blockIdx.x;
  const int xcd = wg & 7, idx = wg >> 3;
  const int bx = xcd * 8 + (idx & 7);
  const int by = idx >> 3;
  const int r0 = bx * 128;
  const int c0 = by * 128;
  const char* asrc = (const char*)(A + (size_t)r0 * KDIM);
  const char* bsrc = (const char*)(Bw + (size_t)c0 * KDIM);

  f32x4 acc[4][4] = {};

  auto stage = [&](int buf, int kt) {
    const size_t kb = (size_t)kt * 128;
#pragma unroll
    for (int i = 0; i < 4; ++i) {
      int L = i * 4096 + tid * 16;
      int r = L >> 7;
      int coff = (L & 127) ^ ((r & 7) << 4);
      gload16(asrc + (size_t)r * 2560 + kb + coff, &smem[buf][0][L]);
      gload16(bsrc + (size_t)r * 2560 + kb + coff, &smem[buf][1][L]);
    }
  };

  auto compute = [&](int buf) {
#pragma unroll
    for (int kk = 0; kk < 2; ++kk) {
      const int cb = (kk * 64 + lg * 16) ^ sxz;
      bf16x8 af[4], bfr[4];
#pragma unroll
      for (int rf = 0; rf < 4; ++rf)
        af[rf] = *reinterpret_cast<const bf16x8*>(&smem[buf][0][(rowblk + rf * 16 + lr) * 128 + cb]);
#pragma unroll
      for (int cf = 0; cf < 4; ++cf)
        bfr[cf] = *reinterpret_cast<const bf16x8*>(&smem[buf][1][(colblk + cf * 16 + lr) * 128 + cb]);
#pragma unroll
      for (int rf = 0; rf < 4; ++rf)
#pragma unroll
        for (int cf = 0; cf < 4; ++cf)
          acc[rf][cf] = mfma_bf16(af[rf], bfr[cf], acc[rf][cf]);
    }
  };

  stage(0, 0);
  asm volatile("s_waitcnt vmcnt(0)" ::: "memory");
  __builtin_amdgcn_s_barrier();
  __builtin_amdgcn_sched_barrier(0);

  for (int t = 0; t < 20; ++t) {
    const int buf = t & 1;
    if (t < 19) {
      stage(buf ^ 1, t + 1);
      asm volatile("s_waitcnt vmcnt(8)" ::: "memory");
    } else {
      asm volatile("s_waitcnt vmcnt(0)" ::: "memory");
    }
    __builtin_amdgcn_sched_barrier(0);
    __builtin_amdgcn_s_barrier();
    __builtin_amdgcn_sched_barrier(0);

    compute(buf);

    __builtin_amdgcn_sched_barrier(0);
    __builtin_amdgcn_s_barrier();
    __builtin_amdgcn_sched_barrier(0);
  }

  float biasr[4];
#pragma unroll
  for (int cf = 0; cf < 4; ++cf) biasr[cf] = bias[c0 + colblk + cf * 16 + lr];

#pragma unroll
  for (int rf = 0; rf < 4; ++rf)
#pragma unroll
    for (int cf = 0; cf < 4; ++cf) {
      const int c = c0 + colblk + cf * 16 + lr;
#pragma unroll
      for (int j = 0; j < 4; ++j) {
        const int r = r0 + rowblk + rf * 16 + lg * 4 + j;
        outf[(size_t)r * DMODEL + c] = acc[rf][cf][j] + biasr[cf];
      }
    }
}

// ---------------- RoPE in-place on q,k; q additionally pre-scaled by scale*log2e ----------------
__global__ void rope_kernel(__bf16* __restrict__ qw, __bf16* __restrict__ kw,
                            const float* __restrict__ ctab, const float* __restrict__ stab,
                            float qscale)
{
  int idx = blockIdx.x * 256 + threadIdx.x;  // 2*64*2048*10 threads
  const int j = idx % 10;
  int rest = idx / 10;
  const int s = rest & (S_LEN - 1);
  rest >>= 11;
  const int bh = rest & 63;
  const int isk = rest >> 6;
  __bf16* base = (isk ? kw : qw) + ((size_t)bh * S_LEN + s) * DHEAD;
  const float4 c4 = *reinterpret_cast<const float4*>(ctab + s * 40 + j * 4);
  const float4 s4 = *reinterpret_cast<const float4*>(stab + s * 40 + j * 4);
  bf16x4 a = *reinterpret_cast<bf16x4*>(base + j * 4);
  bf16x4 b = *reinterpret_cast<bf16x4*>(base + 40 + j * 4);
  const float m = isk ? 1.0f : qscale;
  const float cc[4] = {c4.x, c4.y, c4.z, c4.w};
  const float ss[4] = {s4.x, s4.y, s4.z, s4.w};
#pragma unroll
  for (int t = 0; t < 4; ++t) {
    float fa = (float)a[t], fb = (float)b[t];
    a[t] = (__bf16)((fa * cc[t] - fb * ss[t]) * m);
    b[t] = (__bf16)((fb * cc[t] + fa * ss[t]) * m);
  }
  *reinterpret_cast<bf16x4*>(base + j * 4) = a;
  *reinterpret_cast<bf16x4*>(base + 40 + j * 4) = b;
}

// ---------------- attention v5 (unchanged from R9) ----------------
__global__ __launch_bounds__(256, 3) void attn_kernel(
    const __bf16* __restrict__ qw, const __bf16* __restrict__ kw,
    const __bf16* __restrict__ vtw, __bf16* __restrict__ ow,
    const float* __restrict__ zp)
{
  __shared__ __align__(1024) char smem[2][24576];  // [buf][K 12KB | V 12KB]

  const int tid = threadIdx.x;
  const int lane = tid & 63;
  const int w = tid >> 6;             // 0..3
  const int lr = lane & 15, lg = lane >> 4;

  const int wg = blockIdx.x;          // 0..1023
  const int local = wg >> 3;
  const int bh = (wg & 7) * 8 + (local >> 4);
  const int qt = local & 15;

  const char* qbase = (const char*)(qw + ((size_t)bh * S_LEN + qt * 128) * DHEAD);
  const char* kbase = (const char*)(kw + (size_t)bh * S_LEN * DHEAD);
  const char* vbase = (const char*)(vtw + (size_t)bh * DHEAD * S_LEN);
  const char* zpb = (const char*)zp;

  bf16x8 z8, one8;
#pragma unroll
  for (int i = 0; i < 8; ++i) { z8[i] = (__bf16)0.0f; one8[i] = (__bf16)1.0f; }

  bf16x8 aq[2][3];
#pragma unroll
  for (int m = 0; m < 2; ++m) {
    const char* rp = qbase + (size_t)(w * 32 + m * 16 + lr) * 160;
    aq[m][0] = *reinterpret_cast<const bf16x8*>(rp + lg * 16);
    aq[m][1] = *reinterpret_cast<const bf16x8*>(rp + 64 + lg * 16);
    aq[m][2] = (lg < 2) ? *reinterpret_cast<const bf16x8*>(rp + 128 + lg * 16) : z8;
  }

  const char* src[6];
  size_t step[6];
#pragma unroll
  for (int i = 0; i < 6; ++i) {
    const int s = w * 6 + i;
    if (s < 12) {
      const int ks = s >> 2, n = s & 3;
      if (ks == 2 && lg >= 2) { src[i] = zpb + lane * 16; step[i] = 0; }
      else { src[i] = kbase + (size_t)(n * 16 + lr) * 160 + ks * 64 + lg * 16; step[i] = 64 * 160; }
    } else {
      const int v = s - 12, mf = v >> 1, ks2 = v & 1;
      if (mf == 5) { src[i] = zpb + lane * 16; step[i] = 0; }
      else { src[i] = vbase + (size_t)(mf * 16 + lr) * 4096 + (size_t)(ks2 * 32 + lg * 8) * 2; step[i] = 128; }
    }
  }

  auto stage = [&](int buf) {
#pragma unroll
    for (int i = 0; i < 6; ++i) {
      gload16(src[i], &smem[buf][(w * 6 + i) * 1024]);
      src[i] += step[i];
    }
  };

  f32x4 accO[5][2] = {};  // O[dh = mf*16+lg*4+j][q = w*32 + m*16 + lr]
  f32x4 accD[2] = {};     // den(q=lr) in every lane/reg via ones-MFMA

  stage(0);
  asm volatile("s_waitcnt vmcnt(0)" ::: "memory");
  __builtin_amdgcn_s_barrier();
  __builtin_amdgcn_sched_barrier(0);

  for (int t = 0; t < 32; ++t) {
    const int buf = t & 1;
    if (t < 31) {
      stage(buf ^ 1);                                  // prefetch stays in flight
      asm volatile("s_waitcnt vmcnt(6)" ::: "memory"); // tile t landed; t+1 flying
    } else {
      asm volatile("s_waitcnt vmcnt(0)" ::: "memory");
    }
    __builtin_amdgcn_sched_barrier(0);
    __builtin_amdgcn_s_barrier();   // tile t visible to all waves
    __builtin_amdgcn_sched_barrier(0);

    const char* Kb = smem[buf];
    const char* Vb = smem[buf] + 12288;

    // S^T = K * Q^T  (Q pre-scaled by scale*log2e, so p = exp2(s))
    f32x4 sc[2][4] = {};
#pragma unroll
    for (int n = 0; n < 4; ++n) {
      bf16x8 af0 = *reinterpret_cast<const bf16x8*>(Kb + (0 * 4 + n) * 1024 + lane * 16);
      bf16x8 af1 = *reinterpret_cast<const bf16x8*>(Kb + (1 * 4 + n) * 1024 + lane * 16);
      bf16x8 af2 = *reinterpret_cast<const bf16x8*>(Kb + (2 * 4 + n) * 1024 + lane * 16);
#pragma unroll
      for (int m = 0; m < 2; ++m) {
        sc[m][n] = mfma_bf16(af0, aq[m][0], sc[m][n]);
        sc[m][n] = mfma_bf16(af1, aq[m][1], sc[m][n]);
        sc[m][n] = mfma_bf16(af2, aq[m][2], sc[m][n]);
      }
    }

    // p = exp2(s); lane-local P pack (permuted k-order)
    bf16x8 bp[2][2];
#pragma unroll
    for (int m = 0; m < 2; ++m)
#pragma unroll
      for (int n = 0; n < 4; ++n) {
#pragma unroll
        for (int j = 0; j < 4; ++j)
          bp[m][n >> 1][(n & 1) * 4 + j] = (__bf16)__builtin_amdgcn_exp2f(sc[m][n][j]);
      }

    // O += P*V (V pre-permuted in global); den += ones*P on the MFMA pipe
#pragma unroll
    for (int ks2 = 0; ks2 < 2; ++ks2) {
#pragma unroll
      for (int mf = 0; mf < 5; ++mf) {
        bf16x8 av = *reinterpret_cast<const bf16x8*>(Vb + (mf * 2 + ks2) * 1024 + lane * 16);
        accO[mf][0] = mfma_bf16(av, bp[0][ks2], accO[mf][0]);
        accO[mf][1] = mfma_bf16(av, bp[1][ks2], accO[mf][1]);
      }
      accD[0] = mfma_bf16(one8, bp[0][ks2], accD[0]);
      accD[1] = mfma_bf16(one8, bp[1][ks2], accD[1]);
    }

    __builtin_amdgcn_sched_barrier(0);
    __builtin_amdgcn_s_barrier();   // reads done -> next iter may overwrite buf^1
    __builtin_amdgcn_sched_barrier(0);
  }

  __syncthreads();

  float rinv[2];
#pragma unroll
  for (int m = 0; m < 2; ++m) rinv[m] = 1.0f / accD[m][0];

  char* sOut = smem[0];
#pragma unroll
  for (int mf = 0; mf < 5; ++mf)
#pragma unroll
    for (int m = 0; m < 2; ++m) {
      bf16x4 o4;
#pragma unroll
      for (int j = 0; j < 4; ++j) o4[j] = (__bf16)(accO[mf][m][j] * rinv[m]);
      *reinterpret_cast<bf16x4*>(sOut + (size_t)(w * 32 + m * 16 + lr) * 160 + (mf * 16 + lg * 4) * 2) = o4;
    }
  __syncthreads();

  const int b = bh >> 4, h = bh & 15;
#pragma unroll
  for (int i = 0; i < 5; ++i) {
    int c = i * 256 + tid;
    int row = c / 10, slot = c - row * 10;
    int token = (qt * 128 + row) * 4 + b;
    *reinterpret_cast<bf16x8*>((char*)ow + (size_t)token * 2560 + h * 160 + slot * 16) =
        *reinterpret_cast<const bf16x8*>(sOut + row * 160 + slot * 16);
  }
}

// ---------------- launcher ----------------
extern "C" void kernel_launch(void* const* d_in, const int* in_sizes, int n_in,
                              void* d_out, int out_size, void* d_ws, size_t ws_size,
                              hipStream_t stream)
{
  const float* hidden = (const float*)d_in[0];
  const float* rot    = (const float*)d_in[1];
  const float* w1     = (const float*)d_in[2];
  const float* b1     = (const float*)d_in[3];
  const float* w2     = (const float*)d_in[4];
  const float* b2     = (const float*)d_in[5];
  float* out = (float*)d_out;

  char* ws = (char*)d_ws;
  __bf16* Xbf  = (__bf16*)(ws);                 // 8192x1280 bf16      = 20,971,520 B
  __bf16* W1bf = (__bf16*)(ws + 20971520);      // 3840x1280 bf16      =  9,830,400 B
  __bf16* W2bf = (__bf16*)(ws + 30801920);      // 1280x1280 bf16      =  3,276,800 B
  float*  ctab = (float*)(ws + 34078720);       // 2048x40 f32         =    327,680 B
  float*  stab = (float*)(ws + 34406400);       //                     =    327,680 B
  __bf16* qwp  = (__bf16*)(ws + 34734080);      // [B,H,S,80] bf16     = 20,971,520 B
  __bf16* kwp  = (__bf16*)(ws + 55705600);      // [B,H,S,80] bf16     = 20,971,520 B
  __bf16* vtwp = (__bf16*)(ws + 76677120);      // [B,H,80,S] bf16 (sigma-permuted) = 20,971,520 B
  __bf16* owp  = (__bf16*)(ws + 97648640);      // [S*B,1280] bf16     = 20,971,520 B
  float*  zp   = (float*)(ws + 118620160);      // 4KB zero page

  cast_f32_to_bf16<<<10240, 256, 0, stream>>>(hidden, Xbf, 2621440);
  cast_f32_to_bf16<<<4800, 256, 0, stream>>>(w1, W1bf, 1228800);
  cast_f32_to_bf16<<<1600, 256, 0, stream>>>(w2, W2bf, 409600);
  build_sincos<<<320, 256, 0, stream>>>(rot, ctab, stab, 81920);
  zero_fill<<<4, 256, 0, stream>>>(zp, 1024);

  gemm_qkv256<<<480, 512, 0, stream>>>(Xbf, W1bf, b1, qwp, kwp, vtwp);

  const float qscale = 1.4426950408889634f / sqrtf(80.0f);  // scale * log2(e), folded into Q
  rope_kernel<<<10240, 256, 0, stream>>>(qwp, kwp, ctab, stab, qscale);

  attn_kernel<<<1024, 256, 0, stream>>>(qwp, kwp, vtwp, owp, zp);

  gemm_bt<1><<<640, 256, 0, stream>>>(owp, W2bf, b2, out);
}

// Round 11
// 252.510 us; speedup vs baseline: 1.0889x; 1.0857x over previous
//
#include <hip/hip_runtime.h>
#include <hip/hip_bf16.h>
#include <math.h>

typedef __bf16 bf16x4 __attribute__((ext_vector_type(4)));
typedef __bf16 bf16x8 __attribute__((ext_vector_type(8)));
typedef float  f32x4  __attribute__((ext_vector_type(4)));

#define S_LEN 2048
#define BATCH 4
#define DMODEL 1280
#define NHEAD 16
#define DHEAD 80
#define KDIM 1280

__device__ __forceinline__ f32x4 mfma_bf16(bf16x8 a, bf16x8 b, f32x4 c) {
  return __builtin_amdgcn_mfma_f32_16x16x32_bf16(a, b, c, 0, 0, 0);
}

__device__ __forceinline__ void gload16(const void* g, void* l) {
  __builtin_amdgcn_global_load_lds(
      (const __attribute__((address_space(1))) unsigned int*)g,
      (__attribute__((address_space(3))) unsigned int*)l, 16, 0, 0);
}

// ---------------- fp32 -> bf16 cast (vectorized) ----------------
__global__ void cast_f32_to_bf16(const float* __restrict__ in,
                                 __bf16* __restrict__ out, int n4) {
  int i = blockIdx.x * 256 + threadIdx.x;
  if (i >= n4) return;
  float4 v = reinterpret_cast<const float4*>(in)[i];
  bf16x4 o;
  o[0] = (__bf16)v.x; o[1] = (__bf16)v.y; o[2] = (__bf16)v.z; o[3] = (__bf16)v.w;
  reinterpret_cast<bf16x4*>(out)[i] = o;
}

// ---------------- sin/cos tables [S][40] ----------------
__global__ void build_sincos(const float* __restrict__ rot,
                             float* __restrict__ ctab, float* __restrict__ stab, int n) {
  int i = blockIdx.x * 256 + threadIdx.x;
  if (i >= n) return;
  float v = rot[i];
  ctab[i] = cosf(v);
  stab[i] = sinf(v);
}

// ---------------- zero page ----------------
__global__ void zero_fill(float* __restrict__ p, int n) {
  int i = blockIdx.x * 256 + threadIdx.x;
  if (i < n) p[i] = 0.0f;
}

// ---------------- QKV GEMM, 128x128 tile, BK=64, 4 waves, SINGLE 32KB buffer ----------------
// R9 main loop (known-best 110 us) + NEW epilogue: C-tile staged to LDS (bf16, bias
// added, col-XOR swizzle), then 16B vector stores: q/k as row-chunks (8-col chunks
// never straddle the 80-wide head boundary: 8|80), V gathered along the token axis
// (each (channel,b) covers one full sigma-permuted 32-chunk = contiguous 64B in vtw).
// Replaces 64 scalar 2B global stores/thread with 8 vector stores/thread.
__global__ __launch_bounds__(256, 4) void gemm_qkv128(
    const __bf16* __restrict__ A, const __bf16* __restrict__ Bw,
    const float* __restrict__ bias,
    __bf16* __restrict__ qw, __bf16* __restrict__ kw, __bf16* __restrict__ vtw)
{
  __shared__ __align__(1024) char smem[32768];  // A 16KB | B 16KB; reused as C-tile in epilogue
  const int tid = threadIdx.x;
  const int lane = tid & 63;
  const int w = tid >> 6;             // 0..3
  const int lr = lane & 15, lg = lane >> 4;
  const int wr = w >> 1, wc = w & 1;  // wave owns rows wr*64..+64, cols wc*64..+64

  // XCD-chunked swizzle: 8 bx-panels per XCD (A slice 2.6 MB, L2-resident)
  const int wg = blockIdx.x;          // 0..1919
  const int xcd = wg & 7, idx = wg >> 3;  // idx 0..239
  const int bx = xcd * 8 + (idx & 7);
  const int by = idx >> 3;            // 0..29
  const int r0 = bx * 128, c0 = by * 128;
  const char* asrc = (const char*)(A + (size_t)r0 * KDIM);
  const char* bsrc = (const char*)(Bw + (size_t)c0 * KDIM);

  f32x4 acc[4][4] = {};

  for (int t = 0; t < 20; ++t) {
    const size_t kb = (size_t)t * 128;  // byte offset into K dim
    // stage tile t: 8 gload16/thread (A 16KB + B 16KB)
#pragma unroll
    for (int i = 0; i < 8; ++i) {
      const int L = i * 4096 + tid * 16;           // 0..32767
      const int r = (L & 16383) >> 7;              // row within A or B panel
      const int coff = (L & 127) ^ ((r & 7) << 4); // inverse-swizzled source
      const char* s = (L < 16384 ? asrc : bsrc) + (size_t)r * 2560 + kb + coff;
      gload16(s, &smem[L]);
    }
    __syncthreads();  // drains vmcnt+lgkm; other blocks on the CU fill the gap

    // compute tile t
#pragma unroll
    for (int kk = 0; kk < 2; ++kk) {
      bf16x8 af[4], bfr[4];
#pragma unroll
      for (int rf = 0; rf < 4; ++rf) {
        const int row = wr * 64 + rf * 16 + lr;
        af[rf] = *reinterpret_cast<const bf16x8*>(
            &smem[row * 128 + ((kk * 64 + lg * 16) ^ ((row & 7) << 4))]);
      }
#pragma unroll
      for (int cf = 0; cf < 4; ++cf) {
        const int row = wc * 64 + cf * 16 + lr;
        bfr[cf] = *reinterpret_cast<const bf16x8*>(
            &smem[16384 + row * 128 + ((kk * 64 + lg * 16) ^ ((row & 7) << 4))]);
      }
#pragma unroll
      for (int rf = 0; rf < 4; ++rf)
#pragma unroll
        for (int cf = 0; cf < 4; ++cf)
          acc[rf][cf] = mfma_bf16(af[rf], bfr[cf], acc[rf][cf]);
    }
    __syncthreads();  // reads done -> next stage may overwrite
  }

  // ---- epilogue ----
  float biasr[4];
#pragma unroll
  for (int cf = 0; cf < 4; ++cf) biasr[cf] = bias[c0 + wc * 64 + cf * 16 + lr];

  // stage C-tile to LDS: row-major [128 rows][128 cols] bf16, col-XOR swizzle
  // byteoff(row,col) = row*256 + ((col ^ ((row&7)<<3)) << 1)
#pragma unroll
  for (int cf = 0; cf < 4; ++cf) {
    const int col = wc * 64 + cf * 16 + lr;
#pragma unroll
    for (int rf = 0; rf < 4; ++rf)
#pragma unroll
      for (int j = 0; j < 4; ++j) {
        const int row = wr * 64 + rf * 16 + lg * 4 + j;
        *reinterpret_cast<__bf16*>(
            &smem[row * 256 + ((col ^ ((row & 7) << 3)) << 1)]) =
            (__bf16)(acc[rf][cf][j] + biasr[cf]);
      }
  }
  __syncthreads();

  const int which = c0 / DMODEL;          // 0=q, 1=k, 2=v (block-uniform)
  const int ee0 = c0 - which * DMODEL;    // channel base within {q,k,v}

  if (which < 2) {
    __bf16* dst = (which == 0) ? qw : kw;
#pragma unroll
    for (int i = 0; i < 8; ++i) {
      const int cid = i * 256 + tid;      // 0..2047
      const int row = cid >> 4, slot = cid & 15;
      bf16x8 v = *reinterpret_cast<const bf16x8*>(
          &smem[row * 256 + ((slot ^ (row & 7)) << 4)]);
      const int tr = r0 + row;
      const int b = tr & 3, stok = tr >> 2;
      const int ee = ee0 + slot * 8;      // 8-aligned; 8|80 -> never straddles a head
      const int h = ee / DHEAD, dh = ee - h * DHEAD;
      *reinterpret_cast<bf16x8*>(
          &dst[((size_t)(b * NHEAD + h) * S_LEN + stok) * DHEAD + dh]) = v;
    }
  } else {
    const int s0 = r0 >> 2;               // 32-aligned token/4 base
#pragma unroll
    for (int i = 0; i < 8; ++i) {
      const int cid = i * 256 + tid;      // 0..2047
      const int col = cid >> 4;           // channel within tile, 0..127
      const int b = (cid >> 2) & 3, spblk = cid & 3;
      bf16x8 v;
#pragma unroll
      for (int k = 0; k < 8; ++k) {
        const int spl = spblk * 8 + k;
        // inverse sigma: s = (sp&3) | ((sp&24)>>1) | ((sp&4)<<2)
        const int sl = (spl & 3) | ((spl & 24) >> 1) | ((spl & 4) << 2);
        const int row = sl * 4 + b;
        v[k] = *reinterpret_cast<const __bf16*>(
            &smem[row * 256 + ((col ^ ((row & 7) << 3)) << 1)]);
      }
      const int ee = ee0 + col;
      const int h = ee / DHEAD, dh = ee - h * DHEAD;
      *reinterpret_cast<bf16x8*>(
          &vtw[((size_t)(b * NHEAD + h) * DHEAD + dh) * S_LEN + s0 + spblk * 8]) = v;
    }
  }
}

// ---------------- out-proj GEMM (128x128, unchanged) ----------------
template <int MODE>
__global__ __launch_bounds__(256) void gemm_bt(
    const __bf16* __restrict__ A, const __bf16* __restrict__ Bw,
    const float* __restrict__ bias, float* __restrict__ outf)
{
  __shared__ __align__(16) char smem[2][2][16384];
  const int tid = threadIdx.x;
  const int lane = tid & 63;
  const int w = tid >> 6;
  const int lr = lane & 15, lg = lane >> 4;
  const int rowblk = (w >> 1) * 64, colblk = (w & 1) * 64;
  const int sxz = (lane & 7) << 4;

  const int wg = blockIdx.x;
  const int xcd = wg & 7, idx = wg >> 3;
  const int bx = xcd * 8 + (idx & 7);
  const int by = idx >> 3;
  const int r0 = bx * 128;
  const int c0 = by * 128;
  const char* asrc = (const char*)(A + (size_t)r0 * KDIM);
  const char* bsrc = (const char*)(Bw + (size_t)c0 * KDIM);

  f32x4 acc[4][4] = {};

  auto stage = [&](int buf, int kt) {
    const size_t kb = (size_t)kt * 128;
#pragma unroll
    for (int i = 0; i < 4; ++i) {
      int L = i * 4096 + tid * 16;
      int r = L >> 7;
      int coff = (L & 127) ^ ((r & 7) << 4);
      gload16(asrc + (size_t)r * 2560 + kb + coff, &smem[buf][0][L]);
      gload16(bsrc + (size_t)r * 2560 + kb + coff, &smem[buf][1][L]);
    }
  };

  auto compute = [&](int buf) {
#pragma unroll
    for (int kk = 0; kk < 2; ++kk) {
      const int cb = (kk * 64 + lg * 16) ^ sxz;
      bf16x8 af[4], bfr[4];
#pragma unroll
      for (int rf = 0; rf < 4; ++rf)
        af[rf] = *reinterpret_cast<const bf16x8*>(&smem[buf][0][(rowblk + rf * 16 + lr) * 128 + cb]);
#pragma unroll
      for (int cf = 0; cf < 4; ++cf)
        bfr[cf] = *reinterpret_cast<const bf16x8*>(&smem[buf][1][(colblk + cf * 16 + lr) * 128 + cb]);
#pragma unroll
      for (int rf = 0; rf < 4; ++rf)
#pragma unroll
        for (int cf = 0; cf < 4; ++cf)
          acc[rf][cf] = mfma_bf16(af[rf], bfr[cf], acc[rf][cf]);
    }
  };

  stage(0, 0);
  asm volatile("s_waitcnt vmcnt(0)" ::: "memory");
  __builtin_amdgcn_s_barrier();
  __builtin_amdgcn_sched_barrier(0);

  for (int t = 0; t < 20; ++t) {
    const int buf = t & 1;
    if (t < 19) {
      stage(buf ^ 1, t + 1);
      asm volatile("s_waitcnt vmcnt(8)" ::: "memory");
    } else {
      asm volatile("s_waitcnt vmcnt(0)" ::: "memory");
    }
    __builtin_amdgcn_sched_barrier(0);
    __builtin_amdgcn_s_barrier();
    __builtin_amdgcn_sched_barrier(0);

    compute(buf);

    __builtin_amdgcn_sched_barrier(0);
    __builtin_amdgcn_s_barrier();
    __builtin_amdgcn_sched_barrier(0);
  }

  float biasr[4];
#pragma unroll
  for (int cf = 0; cf < 4; ++cf) biasr[cf] = bias[c0 + colblk + cf * 16 + lr];

#pragma unroll
  for (int rf = 0; rf < 4; ++rf)
#pragma unroll
    for (int cf = 0; cf < 4; ++cf) {
      const int c = c0 + colblk + cf * 16 + lr;
#pragma unroll
      for (int j = 0; j < 4; ++j) {
        const int r = r0 + rowblk + rf * 16 + lg * 4 + j;
        outf[(size_t)r * DMODEL + c] = acc[rf][cf][j] + biasr[cf];
      }
    }
}

// ---------------- RoPE in-place on q,k; q additionally pre-scaled by scale*log2e ----------------
__global__ void rope_kernel(__bf16* __restrict__ qw, __bf16* __restrict__ kw,
                            const float* __restrict__ ctab, const float* __restrict__ stab,
                            float qscale)
{
  int idx = blockIdx.x * 256 + threadIdx.x;  // 2*64*2048*10 threads
  const int j = idx % 10;
  int rest = idx / 10;
  const int s = rest & (S_LEN - 1);
  rest >>= 11;
  const int bh = rest & 63;
  const int isk = rest >> 6;
  __bf16* base = (isk ? kw : qw) + ((size_t)bh * S_LEN + s) * DHEAD;
  const float4 c4 = *reinterpret_cast<const float4*>(ctab + s * 40 + j * 4);
  const float4 s4 = *reinterpret_cast<const float4*>(stab + s * 40 + j * 4);
  bf16x4 a = *reinterpret_cast<bf16x4*>(base + j * 4);
  bf16x4 b = *reinterpret_cast<bf16x4*>(base + 40 + j * 4);
  const float m = isk ? 1.0f : qscale;
  const float cc[4] = {c4.x, c4.y, c4.z, c4.w};
  const float ss[4] = {s4.x, s4.y, s4.z, s4.w};
#pragma unroll
  for (int t = 0; t < 4; ++t) {
    float fa = (float)a[t], fb = (float)b[t];
    a[t] = (__bf16)((fa * cc[t] - fb * ss[t]) * m);
    b[t] = (__bf16)((fb * cc[t] + fa * ss[t]) * m);
  }
  *reinterpret_cast<bf16x4*>(base + j * 4) = a;
  *reinterpret_cast<bf16x4*>(base + 40 + j * 4) = b;
}

// ---------------- attention v5 (unchanged) ----------------
__global__ __launch_bounds__(256, 3) void attn_kernel(
    const __bf16* __restrict__ qw, const __bf16* __restrict__ kw,
    const __bf16* __restrict__ vtw, __bf16* __restrict__ ow,
    const float* __restrict__ zp)
{
  __shared__ __align__(1024) char smem[2][24576];  // [buf][K 12KB | V 12KB]

  const int tid = threadIdx.x;
  const int lane = tid & 63;
  const int w = tid >> 6;             // 0..3
  const int lr = lane & 15, lg = lane >> 4;

  const int wg = blockIdx.x;          // 0..1023
  const int local = wg >> 3;
  const int bh = (wg & 7) * 8 + (local >> 4);
  const int qt = local & 15;

  const char* qbase = (const char*)(qw + ((size_t)bh * S_LEN + qt * 128) * DHEAD);
  const char* kbase = (const char*)(kw + (size_t)bh * S_LEN * DHEAD);
  const char* vbase = (const char*)(vtw + (size_t)bh * DHEAD * S_LEN);
  const char* zpb = (const char*)zp;

  bf16x8 z8, one8;
#pragma unroll
  for (int i = 0; i < 8; ++i) { z8[i] = (__bf16)0.0f; one8[i] = (__bf16)1.0f; }

  bf16x8 aq[2][3];
#pragma unroll
  for (int m = 0; m < 2; ++m) {
    const char* rp = qbase + (size_t)(w * 32 + m * 16 + lr) * 160;
    aq[m][0] = *reinterpret_cast<const bf16x8*>(rp + lg * 16);
    aq[m][1] = *reinterpret_cast<const bf16x8*>(rp + 64 + lg * 16);
    aq[m][2] = (lg < 2) ? *reinterpret_cast<const bf16x8*>(rp + 128 + lg * 16) : z8;
  }

  const char* src[6];
  size_t step[6];
#pragma unroll
  for (int i = 0; i < 6; ++i) {
    const int s = w * 6 + i;
    if (s < 12) {
      const int ks = s >> 2, n = s & 3;
      if (ks == 2 && lg >= 2) { src[i] = zpb + lane * 16; step[i] = 0; }
      else { src[i] = kbase + (size_t)(n * 16 + lr) * 160 + ks * 64 + lg * 16; step[i] = 64 * 160; }
    } else {
      const int v = s - 12, mf = v >> 1, ks2 = v & 1;
      if (mf == 5) { src[i] = zpb + lane * 16; step[i] = 0; }
      else { src[i] = vbase + (size_t)(mf * 16 + lr) * 4096 + (size_t)(ks2 * 32 + lg * 8) * 2; step[i] = 128; }
    }
  }

  auto stage = [&](int buf) {
#pragma unroll
    for (int i = 0; i < 6; ++i) {
      gload16(src[i], &smem[buf][(w * 6 + i) * 1024]);
      src[i] += step[i];
    }
  };

  f32x4 accO[5][2] = {};  // O[dh = mf*16+lg*4+j][q = w*32 + m*16 + lr]
  f32x4 accD[2] = {};     // den(q=lr) in every lane/reg via ones-MFMA

  stage(0);
  asm volatile("s_waitcnt vmcnt(0)" ::: "memory");
  __builtin_amdgcn_s_barrier();
  __builtin_amdgcn_sched_barrier(0);

  for (int t = 0; t < 32; ++t) {
    const int buf = t & 1;
    if (t < 31) {
      stage(buf ^ 1);                                  // prefetch stays in flight
      asm volatile("s_waitcnt vmcnt(6)" ::: "memory"); // tile t landed; t+1 flying
    } else {
      asm volatile("s_waitcnt vmcnt(0)" ::: "memory");
    }
    __builtin_amdgcn_sched_barrier(0);
    __builtin_amdgcn_s_barrier();   // tile t visible to all waves
    __builtin_amdgcn_sched_barrier(0);

    const char* Kb = smem[buf];
    const char* Vb = smem[buf] + 12288;

    // S^T = K * Q^T  (Q pre-scaled by scale*log2e, so p = exp2(s))
    f32x4 sc[2][4] = {};
#pragma unroll
    for (int n = 0; n < 4; ++n) {
      bf16x8 af0 = *reinterpret_cast<const bf16x8*>(Kb + (0 * 4 + n) * 1024 + lane * 16);
      bf16x8 af1 = *reinterpret_cast<const bf16x8*>(Kb + (1 * 4 + n) * 1024 + lane * 16);
      bf16x8 af2 = *reinterpret_cast<const bf16x8*>(Kb + (2 * 4 + n) * 1024 + lane * 16);
#pragma unroll
      for (int m = 0; m < 2; ++m) {
        sc[m][n] = mfma_bf16(af0, aq[m][0], sc[m][n]);
        sc[m][n] = mfma_bf16(af1, aq[m][1], sc[m][n]);
        sc[m][n] = mfma_bf16(af2, aq[m][2], sc[m][n]);
      }
    }

    // p = exp2(s); lane-local P pack (permuted k-order)
    bf16x8 bp[2][2];
#pragma unroll
    for (int m = 0; m < 2; ++m)
#pragma unroll
      for (int n = 0; n < 4; ++n) {
#pragma unroll
        for (int j = 0; j < 4; ++j)
          bp[m][n >> 1][(n & 1) * 4 + j] = (__bf16)__builtin_amdgcn_exp2f(sc[m][n][j]);
      }

    // O += P*V (V pre-permuted in global); den += ones*P on the MFMA pipe
#pragma unroll
    for (int ks2 = 0; ks2 < 2; ++ks2) {
#pragma unroll
      for (int mf = 0; mf < 5; ++mf) {
        bf16x8 av = *reinterpret_cast<const bf16x8*>(Vb + (mf * 2 + ks2) * 1024 + lane * 16);
        accO[mf][0] = mfma_bf16(av, bp[0][ks2], accO[mf][0]);
        accO[mf][1] = mfma_bf16(av, bp[1][ks2], accO[mf][1]);
      }
      accD[0] = mfma_bf16(one8, bp[0][ks2], accD[0]);
      accD[1] = mfma_bf16(one8, bp[1][ks2], accD[1]);
    }

    __builtin_amdgcn_sched_barrier(0);
    __builtin_amdgcn_s_barrier();   // reads done -> next iter may overwrite buf^1
    __builtin_amdgcn_sched_barrier(0);
  }

  __syncthreads();

  float rinv[2];
#pragma unroll
  for (int m = 0; m < 2; ++m) rinv[m] = 1.0f / accD[m][0];

  char* sOut = smem[0];
#pragma unroll
  for (int mf = 0; mf < 5; ++mf)
#pragma unroll
    for (int m = 0; m < 2; ++m) {
      bf16x4 o4;
#pragma unroll
      for (int j = 0; j < 4; ++j) o4[j] = (__bf16)(accO[mf][m][j] * rinv[m]);
      *reinterpret_cast<bf16x4*>(sOut + (size_t)(w * 32 + m * 16 + lr) * 160 + (mf * 16 + lg * 4) * 2) = o4;
    }
  __syncthreads();

  const int b = bh >> 4, h = bh & 15;
#pragma unroll
  for (int i = 0; i < 5; ++i) {
    int c = i * 256 + tid;
    int row = c / 10, slot = c - row * 10;
    int token = (qt * 128 + row) * 4 + b;
    *reinterpret_cast<bf16x8*>((char*)ow + (size_t)token * 2560 + h * 160 + slot * 16) =
        *reinterpret_cast<const bf16x8*>(sOut + row * 160 + slot * 16);
  }
}

// ---------------- launcher ----------------
extern "C" void kernel_launch(void* const* d_in, const int* in_sizes, int n_in,
                              void* d_out, int out_size, void* d_ws, size_t ws_size,
                              hipStream_t stream)
{
  const float* hidden = (const float*)d_in[0];
  const float* rot    = (const float*)d_in[1];
  const float* w1     = (const float*)d_in[2];
  const float* b1     = (const float*)d_in[3];
  const float* w2     = (const float*)d_in[4];
  const float* b2     = (const float*)d_in[5];
  float* out = (float*)d_out;

  char* ws = (char*)d_ws;
  __bf16* Xbf  = (__bf16*)(ws);                 // 8192x1280 bf16      = 20,971,520 B
  __bf16* W1bf = (__bf16*)(ws + 20971520);      // 3840x1280 bf16      =  9,830,400 B
  __bf16* W2bf = (__bf16*)(ws + 30801920);      // 1280x1280 bf16      =  3,276,800 B
  float*  ctab = (float*)(ws + 34078720);       // 2048x40 f32         =    327,680 B
  float*  stab = (float*)(ws + 34406400);       //                     =    327,680 B
  __bf16* qwp  = (__bf16*)(ws + 34734080);      // [B,H,S,80] bf16     = 20,971,520 B
  __bf16* kwp  = (__bf16*)(ws + 55705600);      // [B,H,S,80] bf16     = 20,971,520 B
  __bf16* vtwp = (__bf16*)(ws + 76677120);      // [B,H,80,S] bf16 (sigma-permuted) = 20,971,520 B
  __bf16* owp  = (__bf16*)(ws + 97648640);      // [S*B,1280] bf16     = 20,971,520 B
  float*  zp   = (float*)(ws + 118620160);      // 4KB zero page

  cast_f32_to_bf16<<<10240, 256, 0, stream>>>(hidden, Xbf, 2621440);
  cast_f32_to_bf16<<<4800, 256, 0, stream>>>(w1, W1bf, 1228800);
  cast_f32_to_bf16<<<1600, 256, 0, stream>>>(w2, W2bf, 409600);
  build_sincos<<<320, 256, 0, stream>>>(rot, ctab, stab, 81920);
  zero_fill<<<4, 256, 0, stream>>>(zp, 1024);

  gemm_qkv128<<<1920, 256, 0, stream>>>(Xbf, W1bf, b1, qwp, kwp, vtwp);

  const float qscale = 1.4426950408889634f / sqrtf(80.0f);  // scale * log2(e), folded into Q
  rope_kernel<<<10240, 256, 0, stream>>>(qwp, kwp, ctab, stab, qscale);

  attn_kernel<<<1024, 256, 0, stream>>>(qwp, kwp, vtwp, owp, zp);

  gemm_bt<1><<<640, 256, 0, stream>>>(owp, W2bf, b2, out);
}